// Round 8
// baseline (230.769 us; speedup 1.0000x reference)
//
#include <hip/hip_runtime.h>
#include <hip/hip_bf16.h>

// SAKE GNN: B=512 graphs, M=32 atoms, H=128, L=2 layers, F_IN=16.
// R26: split-B. Spill triangulation (R23/24/25: VGPR clamped 128, ~35 regs
// spilled/thread/layer, sched_barrier no-op): allocator puts wreg[8][4]=128
// in the acc half (accum_offset=128) -> arch half capped at 128 < ~160 arch
// working set -> unified demand ~290 > 256 budget. Fix: wreg[4][4]=64 regs
// (nt 0-3) + nt 4-7 staged per-layer into s_we2 LDS (16KB; free headroom:
// 56.7 -> 73.1KB of the 80KB 2-block budget). XOR swizzle col8 ^= lm&7 on
// stage+read makes ds_read_b128 bank-balanced (unswizzled = 16-way conflict).
// bvv[8] dropped (s_be2 per use). Unified demand ~214 <= 256 -> no spill.
// Decisive check: WRITE_SIZE 36.6MB -> ~16KB.
// Ladder: 677(R1) -> 248(R6) -> 222(R8) -> 204(R10) -> 185(R11) -> 181(R16)
// -> 140(R23 spill) -> 135(R24 spill) -> 138(R25 spill, sched_barrier no-op).

#define NB 512

typedef __bf16 bf16x8 __attribute__((ext_vector_type(8)));
typedef __bf16 bf16x2 __attribute__((ext_vector_type(2)));
typedef float f32x4 __attribute__((ext_vector_type(4)));

__device__ __forceinline__ unsigned short f2bf(float f) {
    unsigned int u = __float_as_uint(f);
    u = u + 0x7FFFu + ((u >> 16) & 1u);   // RNE
    return (unsigned short)(u >> 16);
}
__device__ __forceinline__ unsigned int packbf(float lo, float hi) {
    bf16x2 t;
    t.x = (__bf16)lo;                     // RNE hw cvt; pair fuses to v_cvt_pk_bf16_f32
    t.y = (__bf16)hi;
    return __builtin_bit_cast(unsigned int, t);
}
__device__ __forceinline__ float bflo(unsigned int u) { return __uint_as_float(u << 16); }
__device__ __forceinline__ float bfhi(unsigned int u) { return __uint_as_float(u & 0xffff0000u); }
__device__ __forceinline__ float bf2f(unsigned short u) { return __uint_as_float((unsigned int)u << 16); }
__device__ __forceinline__ float silu_f(float v) {
    return v * __builtin_amdgcn_rcpf(1.0f + __expf(-v));
}

// ---------------- weight transpose+bf16 prep into workspace ----------------
// ws layout (each matrix 128x128 = 16384 bf16, stored as WT[n][k] = W[k][n]):
//   l*6 + {0:WaT, 1:WbT, 2:We2T, 3:Wh1aT, 4:Wh1bT, 5:Wh2T}, 12:W_outT, 13:Wn1T
__global__ __launch_bounds__(256) void prep_weights(
        const float* __restrict__ We1, const float* __restrict__ We2,
        const float* __restrict__ Wh1, const float* __restrict__ Wh2,
        const float* __restrict__ W_out, const float* __restrict__ Wn1,
        unsigned short* __restrict__ ws) {
    __shared__ unsigned short t[32][33];
    const int mtx  = blockIdx.x >> 4;       // 0..13
    const int tile = blockIdx.x & 15;
    const int kt = tile >> 2, nt = tile & 3;
    const int tx = threadIdx.x & 31, ty = threadIdx.x >> 5;   // ty 0..7

    const int l    = (mtx < 12) ? (mtx / 6) : 0;
    const int kind = (mtx < 12) ? (mtx % 6) : (6 + (mtx - 12));
    const float* src = nullptr;
    switch (kind) {
        case 0: src = We1 + (size_t)(l*257      )*128; break;  // Wa
        case 1: src = We1 + (size_t)(l*257 + 128)*128; break;  // Wb
        case 2: src = We2 + (size_t)(l*128      )*128; break;
        case 3: src = Wh1 + (size_t)(l*256      )*128; break;  // Wh1a
        case 4: src = Wh1 + (size_t)(l*256 + 128)*128; break;  // Wh1b
        case 5: src = Wh2 + (size_t)(l*128      )*128; break;
        case 6: src = W_out; break;
        case 7: src = Wn1;  break;
    }
    #pragma unroll
    for (int r = 0; r < 4; r++) {
        int k = kt*32 + ty + r*8;
        int n = nt*32 + tx;
        t[tx][ty + r*8] = f2bf(src[(size_t)k*128 + n]);
    }
    __syncthreads();
    unsigned short* dst = ws + ((size_t)mtx << 14);
    #pragma unroll
    for (int r = 0; r < 4; r++) {
        int nl = ty + r*8;
        int n = nt*32 + nl, k = kt*32 + tx;
        dst[(size_t)n*128 + k] = t[nl][tx];
    }
}

#define MFMA16(ACC, A, B) (ACC) = __builtin_amdgcn_mfma_f32_16x16x32_bf16((A), (B), (ACC), 0, 0, 0)

// ---------------- main fused kernel: 256 threads = 4 waves ----------------
__global__ __launch_bounds__(256, 2) void sake_kernel(
    const float* __restrict__ h,   const float* __restrict__ x,
    const float* __restrict__ W_in,const float* __restrict__ b_in,
    const float* __restrict__ We1, const float* __restrict__ be1,
    const float* __restrict__ be2, const float* __restrict__ bh1,
    const float* __restrict__ bh2, const float* __restrict__ b_out,
    const float* __restrict__ bn1, const float* __restrict__ Wn2,
    const float* __restrict__ bn2, const unsigned short* __restrict__ wt,
    float* __restrict__ out)
{
    // LDS: 16512+16896+8704+8704+16384+4096+512+256+1024+32 = 73120 B
    // -> 2 blocks/CU (budget 81920). s_ep overlays s_nd2.
    __shared__ __align__(16) float          s_hg[32*129];     // 16.1 KB fp32 residual
    __shared__ __align__(16) unsigned short s_mimj[32*264];   // 16.9 KB (mi|mj+be1); reused: u / g fp32
    __shared__ __align__(16) unsigned short s_A1[32*136];     // 8.5 KB bf16 A-stage (hgb)
    __shared__ __align__(16) unsigned short s_A2[32*136];     // 8.5 KB bf16 A-stage (agg / ho)
    __shared__ __align__(16) unsigned short s_we2[8192];      // 16 KB We2 rows 64..127, XOR-swizzled
    __shared__ __align__(16) float          s_nd2[32*32];     // 4 KB compacted d2; reused: s_ep
    __shared__ __align__(16) float          s_wd[128];        // 512 B
    __shared__ __align__(16) unsigned short s_be2[128];       // 256 B bf16
    __shared__ __align__(16) unsigned char  s_nbr[32][32];    // 1 KB full neighbor lists
    __shared__ __align__(16) unsigned char  s_cnt[32];        // 32 B

    const int tid  = threadIdx.x;
    const int b    = blockIdx.x;
    const int w    = tid >> 6;        // wave 0..3
    const int lane = tid & 63;
    const int quad = lane >> 4;
    const int lm   = lane & 15;
    const int mt   = w & 1;           // row-half for 32-row GEMMs
    const int ng   = w >> 1;          // col-tile group (0..1)

    // ---- neighbor build: d2 from global x via shfl (wave 0 only) ----
    if (tid < 32) {
        const float xx = x[(b*32+tid)*3+0];
        const float xy = x[(b*32+tid)*3+1];
        const float xz = x[(b*32+tid)*3+2];
        int c = 0;
        for (int j = 0; j < 32; j++) {
            float ox = __shfl(xx, j);
            float oy = __shfl(xy, j);
            float oz = __shfl(xz, j);
            float dx = xx - ox, dy = xy - oy, dz = xz - oz;
            float d2 = dx*dx + dy*dy + dz*dz;
            if (d2 < 1.0f && j != tid) {
                s_nbr[tid][c] = (unsigned char)j; s_nd2[tid*32 + c] = d2; c++;
            }
        }
        for (int q = c; q < 32; q++) { s_nbr[tid][q] = (unsigned char)tid; s_nd2[tid*32 + q] = 0.0f; }
        s_cnt[tid] = (unsigned char)c;
    }
    // ---- hg = h@W_in + b_in (writes BOTH s_hg fp32 and s_A1 bf16) ----
    {
        int k = tid & 127, mg = tid >> 7;   // mg 0..1 -> 16 rows each
        float c0 = W_in[       k], c1 = W_in[ 128+k], c2 = W_in[ 256+k], c3 = W_in[ 384+k];
        float c4 = W_in[ 512+k], c5 = W_in[ 640+k], c6 = W_in[ 768+k], c7 = W_in[ 896+k];
        float c8 = W_in[1024+k], c9 = W_in[1152+k], c10= W_in[1280+k], c11= W_in[1408+k];
        float c12= W_in[1536+k], c13= W_in[1664+k], c14= W_in[1792+k], c15= W_in[1920+k];
        float bi = b_in[k];
        for (int rr = 0; rr < 16; rr++) {
            int m = mg*16 + rr;
            const float4* h4 = (const float4*)(h + (size_t)(b*32 + m)*16);
            float4 h0 = h4[0], h1 = h4[1], h2 = h4[2], h3 = h4[3];
            float acc = bi
                + h0.x*c0  + h0.y*c1  + h0.z*c2  + h0.w*c3
                + h1.x*c4  + h1.y*c5  + h1.z*c6  + h1.w*c7
                + h2.x*c8  + h2.y*c9  + h2.z*c10 + h2.w*c11
                + h3.x*c12 + h3.y*c13 + h3.z*c14 + h3.w*c15;
            s_hg[m*129 + k] = acc;
            s_A1[m*136 + k] = f2bf(acc);
        }
    }
    __syncthreads();

    for (int l = 0; l < 2; l++) {
        // ---- per-layer staging: wd/be2 + We2 rows 64..127 -> s_we2 (swizzled) ----
        if (tid < 128) {
            s_wd[tid]  = We1[(l*257 + 256)*128 + tid];
            s_be2[tid] = f2bf(be2[l*128 + tid]);
        }
        {
            const unsigned short* src = wt + (((size_t)l*6 + 2) << 14) + 8192; // rows 64..127
            int r = tid >> 2, c0 = (tid & 3) * 32;
            #pragma unroll
            for (int k = 0; k < 4; k++) {
                int c  = c0 + k*8;
                int cs = c ^ ((r & 7) * 8);            // XOR swizzle, granule 8 u16
                *(uint4*)&s_we2[r*128 + cs] = *(const uint4*)&src[r*128 + c];
            }
        }

        // ---- mi | mj GEMM: [32x128] @ [Wa | Wb] -> s_mimj (be1 folded into mj) ----
        #pragma unroll 1
        for (int t4 = 0; t4 < 8; t4++) {
            int nt = ng + t4*2;                       // 0..15
            const unsigned short* bt = wt + (((size_t)l*6 + (nt < 8 ? 0 : 1)) << 14);
            int ncl = (nt & 7)*16 + lm;
            f32x4 acc = {0.f,0.f,0.f,0.f};
            #pragma unroll
            for (int kb = 0; kb < 4; kb++) {
                bf16x8 a  = *(const bf16x8*)&s_A1[(mt*16+lm)*136 + kb*32 + quad*8];
                bf16x8 bb = *(const bf16x8*)&bt[ncl*128 + kb*32 + quad*8];
                MFMA16(acc, a, bb);
            }
            int c = nt*16 + lm;
            float bias = (nt >= 8) ? be1[l*128 + ncl] : 0.0f;
            s_mimj[(mt*16 + quad*4 + 0)*264 + c] = f2bf(acc.x + bias);
            s_mimj[(mt*16 + quad*4 + 1)*264 + c] = f2bf(acc.y + bias);
            s_mimj[(mt*16 + quad*4 + 2)*264 + c] = f2bf(acc.z + bias);
            s_mimj[(mt*16 + quad*4 + 3)*264 + c] = f2bf(acc.w + bias);
        }
        __syncthreads();

        // ---- pair phase: silu1 -> tiled sparse @We2 -> silu2 -> mask -> agg ----
        {
            const unsigned short* we2t = wt + (((size_t)l*6 + 2) << 14);
            const unsigned short* bbase = we2t + lm*128 + quad*8;   // + nt*2048
            // half hoist: nt 0..3 in registers (64 VGPR), nt 4..7 from s_we2
            bf16x8 wreg[4][4];
            #pragma unroll
            for (int nt = 0; nt < 4; nt++) {
                #pragma unroll
                for (int kb = 0; kb < 4; kb++)
                    wreg[nt][kb] = *(const bf16x8*)(bbase + nt*2048 + kb*32);
            }
            const int swz = (lm & 7) * 8;

            #pragma unroll 1
            for (int ii = 0; ii < 8; ii++) {
                const int i = ii*4 + w;               // wave owns row i fully
                const int cnt = s_cnt[i];             // wave-uniform
                const int ntile = (cnt > 16) ? 2 : 1; // wave-uniform tile count
                float part8[8] = {0.f,0.f,0.f,0.f,0.f,0.f,0.f,0.f};
#define MAKE_AF(J, KB, AF) { \
    const uint4 miu = *(const uint4*)&s_mimj[i*264 + (KB)*32 + quad*8]; \
    const uint4 mju = *(const uint4*)&s_mimj[(J)*264 + 128 + (KB)*32 + quad*8]; \
    const float4 wa = *(const float4*)&s_wd[(KB)*32 + quad*8]; \
    const float4 wb = *(const float4*)&s_wd[(KB)*32 + quad*8 + 4]; \
    uint4 au; \
    au.x = packbf(silu_f(bflo(miu.x)+bflo(mju.x)+d2v*wa.x), silu_f(bfhi(miu.x)+bfhi(mju.x)+d2v*wa.y)); \
    au.y = packbf(silu_f(bflo(miu.y)+bflo(mju.y)+d2v*wa.z), silu_f(bfhi(miu.y)+bfhi(mju.y)+d2v*wa.w)); \
    au.z = packbf(silu_f(bflo(miu.z)+bflo(mju.z)+d2v*wb.x), silu_f(bfhi(miu.z)+bfhi(mju.z)+d2v*wb.y)); \
    au.w = packbf(silu_f(bflo(miu.w)+bflo(mju.w)+d2v*wb.z), silu_f(bfhi(miu.w)+bfhi(mju.w)+d2v*wb.w)); \
    AF = __builtin_bit_cast(bf16x8, au); }
                #pragma unroll 1
                for (int jt = 0; jt < ntile; jt++) {
                    const int j = s_nbr[i][jt*16 + lm];        // gathered neighbor (pad=self)
                    const float d2v = s_nd2[i*32 + jt*16 + lm];
                    bf16x8 a00, a01, a02, a03;
                    MAKE_AF(j, 0, a00) MAKE_AF(j, 1, a01)
                    MAKE_AF(j, 2, a02) MAKE_AF(j, 3, a03)
                    const int jb0 = jt*16 + quad*4;
                    const float mk00 = (jb0 + 0 < cnt) ? 1.f : 0.f;
                    const float mk01 = (jb0 + 1 < cnt) ? 1.f : 0.f;
                    const float mk02 = (jb0 + 2 < cnt) ? 1.f : 0.f;
                    const float mk03 = (jb0 + 3 < cnt) ? 1.f : 0.f;
                    #pragma unroll
                    for (int nt = 0; nt < 4; nt++) {           // register half
                        f32x4 ac0 = {0.f,0.f,0.f,0.f};
                        MFMA16(ac0, a00, wreg[nt][0]); MFMA16(ac0, a01, wreg[nt][1]);
                        MFMA16(ac0, a02, wreg[nt][2]); MFMA16(ac0, a03, wreg[nt][3]);
                        const float bv = bf2f(s_be2[nt*16 + lm]);
                        part8[nt] += mk00*silu_f(ac0.x + bv) + mk01*silu_f(ac0.y + bv)
                                   + mk02*silu_f(ac0.z + bv) + mk03*silu_f(ac0.w + bv);
                    }
                    #pragma unroll
                    for (int nt = 4; nt < 8; nt++) {           // LDS half (swizzled)
                        const unsigned short* lp = &s_we2[((nt-4)*16 + lm)*128];
                        bf16x8 b0 = *(const bf16x8*)&lp[(0*32 + quad*8) ^ swz];
                        bf16x8 b1 = *(const bf16x8*)&lp[(1*32 + quad*8) ^ swz];
                        bf16x8 b2 = *(const bf16x8*)&lp[(2*32 + quad*8) ^ swz];
                        bf16x8 b3 = *(const bf16x8*)&lp[(3*32 + quad*8) ^ swz];
                        f32x4 ac0 = {0.f,0.f,0.f,0.f};
                        MFMA16(ac0, a00, b0); MFMA16(ac0, a01, b1);
                        MFMA16(ac0, a02, b2); MFMA16(ac0, a03, b3);
                        const float bv = bf2f(s_be2[nt*16 + lm]);
                        part8[nt] += mk00*silu_f(ac0.x + bv) + mk01*silu_f(ac0.y + bv)
                                   + mk02*silu_f(ac0.z + bv) + mk03*silu_f(ac0.w + bv);
                    }
                }
#undef MAKE_AF
                #pragma unroll
                for (int nt = 0; nt < 8; nt++) {
                    float part = part8[nt];
                    part += __shfl_xor(part, 16);
                    part += __shfl_xor(part, 32);
                    if (lane < 16) s_A2[i*136 + nt*16 + lane] = f2bf(part);
                }
            }
        }
        __syncthreads();

        // ---- u = silu(hg@Wh1a + agg@Wh1b + bh1) -> s_u (reuses s_mimj, stride 136) ----
        unsigned short* s_u = s_mimj;
        {
            const unsigned short* w1a = wt + (((size_t)l*6 + 3) << 14);
            const unsigned short* w1b = wt + (((size_t)l*6 + 4) << 14);
#define U_GEMM(T2) { \
    const int nt = ng + (T2)*2, ncl = nt*16 + lm; \
    f32x4 acc = {0.f,0.f,0.f,0.f}; \
    _Pragma("unroll") \
    for (int kb = 0; kb < 4; kb++) { \
        bf16x8 a  = *(const bf16x8*)&s_A1[(mt*16+lm)*136 + kb*32 + quad*8]; \
        bf16x8 bb = *(const bf16x8*)&w1a[ncl*128 + kb*32 + quad*8]; \
        MFMA16(acc, a, bb); } \
    _Pragma("unroll") \
    for (int kb = 0; kb < 4; kb++) { \
        bf16x8 a  = *(const bf16x8*)&s_A2[(mt*16+lm)*136 + kb*32 + quad*8]; \
        bf16x8 bb = *(const bf16x8*)&w1b[ncl*128 + kb*32 + quad*8]; \
        MFMA16(acc, a, bb); } \
    const float bh = bh1[l*128 + ncl]; \
    s_u[(mt*16 + quad*4 + 0)*136 + ncl] = f2bf(silu_f(acc.x + bh)); \
    s_u[(mt*16 + quad*4 + 1)*136 + ncl] = f2bf(silu_f(acc.y + bh)); \
    s_u[(mt*16 + quad*4 + 2)*136 + ncl] = f2bf(silu_f(acc.z + bh)); \
    s_u[(mt*16 + quad*4 + 3)*136 + ncl] = f2bf(silu_f(acc.w + bh)); }
            U_GEMM(0) U_GEMM(1) U_GEMM(2) U_GEMM(3)
#undef U_GEMM
        }
        __syncthreads();

        // ---- hg += u@Wh2 + bh2 (fused: also writes next A1 bf16) ----
        {
            const unsigned short* w2 = wt + (((size_t)l*6 + 5) << 14);
#define H_GEMM(T2) { \
    const int nt = ng + (T2)*2, ncl = nt*16 + lm; \
    f32x4 acc = {0.f,0.f,0.f,0.f}; \
    _Pragma("unroll") \
    for (int kb = 0; kb < 4; kb++) { \
        bf16x8 a  = *(const bf16x8*)&s_u[(mt*16+lm)*136 + kb*32 + quad*8]; \
        bf16x8 bb = *(const bf16x8*)&w2[ncl*128 + kb*32 + quad*8]; \
        MFMA16(acc, a, bb); } \
    const float bh = bh2[l*128 + ncl]; \
    { float v = s_hg[(mt*16 + quad*4 + 0)*129 + ncl] + acc.x + bh; \
      s_hg[(mt*16 + quad*4 + 0)*129 + ncl] = v; s_A1[(mt*16 + quad*4 + 0)*136 + ncl] = f2bf(v); } \
    { float v = s_hg[(mt*16 + quad*4 + 1)*129 + ncl] + acc.y + bh; \
      s_hg[(mt*16 + quad*4 + 1)*129 + ncl] = v; s_A1[(mt*16 + quad*4 + 1)*136 + ncl] = f2bf(v); } \
    { float v = s_hg[(mt*16 + quad*4 + 2)*129 + ncl] + acc.z + bh; \
      s_hg[(mt*16 + quad*4 + 2)*129 + ncl] = v; s_A1[(mt*16 + quad*4 + 2)*136 + ncl] = f2bf(v); } \
    { float v = s_hg[(mt*16 + quad*4 + 3)*129 + ncl] + acc.w + bh; \
      s_hg[(mt*16 + quad*4 + 3)*129 + ncl] = v; s_A1[(mt*16 + quad*4 + 3)*136 + ncl] = f2bf(v); } }
            H_GEMM(0) H_GEMM(1) H_GEMM(2) H_GEMM(3)
#undef H_GEMM
        }
        __syncthreads();
    }

    // ---- output head (A1 already holds bf16(hg) from l=1 H_GEMM) ----
    {   // ho = hg@W_out + b_out -> A2 (bf16)
        const unsigned short* wo = wt + ((size_t)12 << 14);
#define O_GEMM(T2) { \
    const int nt = ng + (T2)*2, ncl = nt*16 + lm; \
    f32x4 acc = {0.f,0.f,0.f,0.f}; \
    _Pragma("unroll") \
    for (int kb = 0; kb < 4; kb++) { \
        bf16x8 a  = *(const bf16x8*)&s_A1[(mt*16+lm)*136 + kb*32 + quad*8]; \
        bf16x8 bb = *(const bf16x8*)&wo[ncl*128 + kb*32 + quad*8]; \
        MFMA16(acc, a, bb); } \
    const float bo = b_out[ncl]; \
    s_A2[(mt*16 + quad*4 + 0)*136 + ncl] = f2bf(acc.x + bo); \
    s_A2[(mt*16 + quad*4 + 1)*136 + ncl] = f2bf(acc.y + bo); \
    s_A2[(mt*16 + quad*4 + 2)*136 + ncl] = f2bf(acc.z + bo); \
    s_A2[(mt*16 + quad*4 + 3)*136 + ncl] = f2bf(acc.w + bo); }
        O_GEMM(0) O_GEMM(1) O_GEMM(2) O_GEMM(3)
#undef O_GEMM
    }
    __syncthreads();
    float* s_g = (float*)s_mimj;                           // reuse (g is 32x129 fp32)
    {   // g = silu(ho@Wn1 + bn1) -> s_g fp32
        const unsigned short* wn1 = wt + ((size_t)13 << 14);
#define G_GEMM(T2) { \
    const int nt = ng + (T2)*2, ncl = nt*16 + lm; \
    f32x4 acc = {0.f,0.f,0.f,0.f}; \
    _Pragma("unroll") \
    for (int kb = 0; kb < 4; kb++) { \
        bf16x8 a  = *(const bf16x8*)&s_A2[(mt*16+lm)*136 + kb*32 + quad*8]; \
        bf16x8 bb = *(const bf16x8*)&wn1[ncl*128 + kb*32 + quad*8]; \
        MFMA16(acc, a, bb); } \
    const float bn = bn1[ncl]; \
    s_g[(mt*16 + quad*4 + 0)*129 + ncl] = silu_f(acc.x + bn); \
    s_g[(mt*16 + quad*4 + 1)*129 + ncl] = silu_f(acc.y + bn); \
    s_g[(mt*16 + quad*4 + 2)*129 + ncl] = silu_f(acc.z + bn); \
    s_g[(mt*16 + quad*4 + 3)*129 + ncl] = silu_f(acc.w + bn); }
        G_GEMM(0) G_GEMM(1) G_GEMM(2) G_GEMM(3)
#undef G_GEMM
    }
    __syncthreads();
    // e = g @ Wn2 + bn2 ; out[b] = sum_m e[m]
    float* s_ep = s_nd2;                                   // reuse (s_nd2 dead)
    {
        int m = tid >> 3, s = tid & 7;
        float acc = 0.f;
        #pragma unroll
        for (int q = 0; q < 16; q++) {
            int hh = s*16 + q;
            acc += s_g[m*129 + hh] * Wn2[hh];
        }
        s_ep[tid] = acc;
    }
    __syncthreads();
    if (tid < 32) {
        float e = bn2[0];
        #pragma unroll
        for (int s = 0; s < 8; s++) e += s_ep[tid*8 + s];
        #pragma unroll
        for (int off = 16; off >= 1; off >>= 1) e += __shfl_down(e, off, 32);
        if (tid == 0) out[b] = e;
    }
}

extern "C" void kernel_launch(void* const* d_in, const int* in_sizes, int n_in,
                              void* d_out, int out_size, void* d_ws, size_t ws_size,
                              hipStream_t stream) {
    const float* h     = (const float*)d_in[0];
    const float* x     = (const float*)d_in[1];
    const float* W_in  = (const float*)d_in[3];
    const float* b_in  = (const float*)d_in[4];
    const float* We1   = (const float*)d_in[5];
    const float* be1   = (const float*)d_in[6];
    const float* We2   = (const float*)d_in[7];
    const float* be2   = (const float*)d_in[8];
    const float* Wh1   = (const float*)d_in[9];
    const float* bh1   = (const float*)d_in[10];
    const float* Wh2   = (const float*)d_in[11];
    const float* bh2   = (const float*)d_in[12];
    const float* W_out = (const float*)d_in[13];
    const float* b_out = (const float*)d_in[14];
    const float* Wn1   = (const float*)d_in[15];
    const float* bn1   = (const float*)d_in[16];
    const float* Wn2   = (const float*)d_in[17];
    const float* bn2   = (const float*)d_in[18];
    unsigned short* ws = (unsigned short*)d_ws;   // needs 14*16384*2 = 448 KB
    float* outp = (float*)d_out;

    prep_weights<<<14*16, 256, 0, stream>>>(We1, We2, Wh1, Wh2, W_out, Wn1, ws);
    sake_kernel<<<NB, 256, 0, stream>>>(h, x, W_in, b_in, We1, be1, be2, bh1, bh2,
                                        b_out, bn1, Wn2, bn2, ws, outp);
}

// Round 9
// 214.597 us; speedup vs baseline: 1.0754x; 1.0754x over previous
//
#include <hip/hip_runtime.h>
#include <hip/hip_bf16.h>

// SAKE GNN: B=512 graphs, M=32 atoms, H=128, L=2 layers, F_IN=16.
// R27: two-pass pair phase. Spill history: R23 wreg[8][4] 33MB, R24 unified
// 36MB, R25 sched_barrier no-op, R26 half-hoist+LDS-half WORSE (55.6MB) --
// falsifies "wreg is spilled". Model: wreg+acc live in AGPR half, allocator
// pins accum_offset=128 -> arch capped 128 < inner-loop arch demand (~160)
// -> arch-side spills. R26 added arch pressure (swz addressing, b0-b3,
// both halves in one body). Fix: cut ARCH demand -- pass 0 computes nt 0-3
// for all rows (wreg[4][4]=64 AGPR), pass 1 reloads wreg (nt 4-7), rebuilds
// af (+32 silu/row, VALUBusy 33% has headroom). Per-pass arch ~90 + 64 AGPR
// ~= 155 unified << 256. No s_we2, no swizzle. Decisive: WRITE_SIZE ~16KB.
// Ladder: 677(R1) -> 248(R6) -> 222(R8) -> 204(R10) -> 185(R11) -> 181(R16)
// -> 140(R23 spill) -> 135(R24 spill) -> 155(R26 worse).

#define NB 512

typedef __bf16 bf16x8 __attribute__((ext_vector_type(8)));
typedef __bf16 bf16x2 __attribute__((ext_vector_type(2)));
typedef float f32x4 __attribute__((ext_vector_type(4)));

__device__ __forceinline__ unsigned short f2bf(float f) {
    unsigned int u = __float_as_uint(f);
    u = u + 0x7FFFu + ((u >> 16) & 1u);   // RNE
    return (unsigned short)(u >> 16);
}
__device__ __forceinline__ unsigned int packbf(float lo, float hi) {
    bf16x2 t;
    t.x = (__bf16)lo;                     // RNE hw cvt; pair fuses to v_cvt_pk_bf16_f32
    t.y = (__bf16)hi;
    return __builtin_bit_cast(unsigned int, t);
}
__device__ __forceinline__ float bflo(unsigned int u) { return __uint_as_float(u << 16); }
__device__ __forceinline__ float bfhi(unsigned int u) { return __uint_as_float(u & 0xffff0000u); }
__device__ __forceinline__ float bf2f(unsigned short u) { return __uint_as_float((unsigned int)u << 16); }
__device__ __forceinline__ float silu_f(float v) {
    return v * __builtin_amdgcn_rcpf(1.0f + __expf(-v));
}

// ---------------- weight transpose+bf16 prep into workspace ----------------
// ws layout (each matrix 128x128 = 16384 bf16, stored as WT[n][k] = W[k][n]):
//   l*6 + {0:WaT, 1:WbT, 2:We2T, 3:Wh1aT, 4:Wh1bT, 5:Wh2T}, 12:W_outT, 13:Wn1T
__global__ __launch_bounds__(256) void prep_weights(
        const float* __restrict__ We1, const float* __restrict__ We2,
        const float* __restrict__ Wh1, const float* __restrict__ Wh2,
        const float* __restrict__ W_out, const float* __restrict__ Wn1,
        unsigned short* __restrict__ ws) {
    __shared__ unsigned short t[32][33];
    const int mtx  = blockIdx.x >> 4;       // 0..13
    const int tile = blockIdx.x & 15;
    const int kt = tile >> 2, nt = tile & 3;
    const int tx = threadIdx.x & 31, ty = threadIdx.x >> 5;   // ty 0..7

    const int l    = (mtx < 12) ? (mtx / 6) : 0;
    const int kind = (mtx < 12) ? (mtx % 6) : (6 + (mtx - 12));
    const float* src = nullptr;
    switch (kind) {
        case 0: src = We1 + (size_t)(l*257      )*128; break;  // Wa
        case 1: src = We1 + (size_t)(l*257 + 128)*128; break;  // Wb
        case 2: src = We2 + (size_t)(l*128      )*128; break;
        case 3: src = Wh1 + (size_t)(l*256      )*128; break;  // Wh1a
        case 4: src = Wh1 + (size_t)(l*256 + 128)*128; break;  // Wh1b
        case 5: src = Wh2 + (size_t)(l*128      )*128; break;
        case 6: src = W_out; break;
        case 7: src = Wn1;  break;
    }
    #pragma unroll
    for (int r = 0; r < 4; r++) {
        int k = kt*32 + ty + r*8;
        int n = nt*32 + tx;
        t[tx][ty + r*8] = f2bf(src[(size_t)k*128 + n]);
    }
    __syncthreads();
    unsigned short* dst = ws + ((size_t)mtx << 14);
    #pragma unroll
    for (int r = 0; r < 4; r++) {
        int nl = ty + r*8;
        int n = nt*32 + nl, k = kt*32 + tx;
        dst[(size_t)n*128 + k] = t[nl][tx];
    }
}

#define MFMA16(ACC, A, B) (ACC) = __builtin_amdgcn_mfma_f32_16x16x32_bf16((A), (B), (ACC), 0, 0, 0)

// ---------------- main fused kernel: 256 threads = 4 waves ----------------
__global__ __launch_bounds__(256, 2) void sake_kernel(
    const float* __restrict__ h,   const float* __restrict__ x,
    const float* __restrict__ W_in,const float* __restrict__ b_in,
    const float* __restrict__ We1, const float* __restrict__ be1,
    const float* __restrict__ be2, const float* __restrict__ bh1,
    const float* __restrict__ bh2, const float* __restrict__ b_out,
    const float* __restrict__ bn1, const float* __restrict__ Wn2,
    const float* __restrict__ bn2, const unsigned short* __restrict__ wt,
    float* __restrict__ out)
{
    // LDS: 16512+16896+8704+8704+4096+512+256+1024+32 = 56736 B (2 blocks/CU)
    __shared__ __align__(16) float          s_hg[32*129];     // 16.1 KB fp32 residual
    __shared__ __align__(16) unsigned short s_mimj[32*264];   // 16.9 KB (mi|mj+be1); reused: u / g fp32
    __shared__ __align__(16) unsigned short s_A1[32*136];     // 8.5 KB bf16 A-stage (hgb)
    __shared__ __align__(16) unsigned short s_A2[32*136];     // 8.5 KB bf16 A-stage (agg / ho)
    __shared__ __align__(16) float          s_nd2[32*32];     // 4 KB compacted d2; reused: s_ep
    __shared__ __align__(16) float          s_wd[128];        // 512 B
    __shared__ __align__(16) unsigned short s_be2[128];       // 256 B bf16
    __shared__ __align__(16) unsigned char  s_nbr[32][32];    // 1 KB full neighbor lists
    __shared__ __align__(16) unsigned char  s_cnt[32];        // 32 B

    const int tid  = threadIdx.x;
    const int b    = blockIdx.x;
    const int w    = tid >> 6;        // wave 0..3
    const int lane = tid & 63;
    const int quad = lane >> 4;
    const int lm   = lane & 15;
    const int mt   = w & 1;           // row-half for 32-row GEMMs
    const int ng   = w >> 1;          // col-tile group (0..1)

    // ---- neighbor build: d2 from global x via shfl (wave 0 only) ----
    if (tid < 32) {
        const float xx = x[(b*32+tid)*3+0];
        const float xy = x[(b*32+tid)*3+1];
        const float xz = x[(b*32+tid)*3+2];
        int c = 0;
        for (int j = 0; j < 32; j++) {
            float ox = __shfl(xx, j);
            float oy = __shfl(xy, j);
            float oz = __shfl(xz, j);
            float dx = xx - ox, dy = xy - oy, dz = xz - oz;
            float d2 = dx*dx + dy*dy + dz*dz;
            if (d2 < 1.0f && j != tid) {
                s_nbr[tid][c] = (unsigned char)j; s_nd2[tid*32 + c] = d2; c++;
            }
        }
        for (int q = c; q < 32; q++) { s_nbr[tid][q] = (unsigned char)tid; s_nd2[tid*32 + q] = 0.0f; }
        s_cnt[tid] = (unsigned char)c;
    }
    // ---- hg = h@W_in + b_in (writes BOTH s_hg fp32 and s_A1 bf16) ----
    {
        int k = tid & 127, mg = tid >> 7;   // mg 0..1 -> 16 rows each
        float c0 = W_in[       k], c1 = W_in[ 128+k], c2 = W_in[ 256+k], c3 = W_in[ 384+k];
        float c4 = W_in[ 512+k], c5 = W_in[ 640+k], c6 = W_in[ 768+k], c7 = W_in[ 896+k];
        float c8 = W_in[1024+k], c9 = W_in[1152+k], c10= W_in[1280+k], c11= W_in[1408+k];
        float c12= W_in[1536+k], c13= W_in[1664+k], c14= W_in[1792+k], c15= W_in[1920+k];
        float bi = b_in[k];
        for (int rr = 0; rr < 16; rr++) {
            int m = mg*16 + rr;
            const float4* h4 = (const float4*)(h + (size_t)(b*32 + m)*16);
            float4 h0 = h4[0], h1 = h4[1], h2 = h4[2], h3 = h4[3];
            float acc = bi
                + h0.x*c0  + h0.y*c1  + h0.z*c2  + h0.w*c3
                + h1.x*c4  + h1.y*c5  + h1.z*c6  + h1.w*c7
                + h2.x*c8  + h2.y*c9  + h2.z*c10 + h2.w*c11
                + h3.x*c12 + h3.y*c13 + h3.z*c14 + h3.w*c15;
            s_hg[m*129 + k] = acc;
            s_A1[m*136 + k] = f2bf(acc);
        }
    }
    __syncthreads();

    for (int l = 0; l < 2; l++) {
        // ---- wd/be2 staging for this layer (read after mimj barrier) ----
        if (tid < 128) {
            s_wd[tid]  = We1[(l*257 + 256)*128 + tid];
            s_be2[tid] = f2bf(be2[l*128 + tid]);
        }

        // ---- mi | mj GEMM: [32x128] @ [Wa | Wb] -> s_mimj (be1 folded into mj) ----
        #pragma unroll 1
        for (int t4 = 0; t4 < 8; t4++) {
            int nt = ng + t4*2;                       // 0..15
            const unsigned short* bt = wt + (((size_t)l*6 + (nt < 8 ? 0 : 1)) << 14);
            int ncl = (nt & 7)*16 + lm;
            f32x4 acc = {0.f,0.f,0.f,0.f};
            #pragma unroll
            for (int kb = 0; kb < 4; kb++) {
                bf16x8 a  = *(const bf16x8*)&s_A1[(mt*16+lm)*136 + kb*32 + quad*8];
                bf16x8 bb = *(const bf16x8*)&bt[ncl*128 + kb*32 + quad*8];
                MFMA16(acc, a, bb);
            }
            int c = nt*16 + lm;
            float bias = (nt >= 8) ? be1[l*128 + ncl] : 0.0f;
            s_mimj[(mt*16 + quad*4 + 0)*264 + c] = f2bf(acc.x + bias);
            s_mimj[(mt*16 + quad*4 + 1)*264 + c] = f2bf(acc.y + bias);
            s_mimj[(mt*16 + quad*4 + 2)*264 + c] = f2bf(acc.z + bias);
            s_mimj[(mt*16 + quad*4 + 3)*264 + c] = f2bf(acc.w + bias);
        }
        __syncthreads();

        // ---- pair phase: two passes over output tiles; per pass only
        //      wreg[4][4] (64 AGPR) + one af set + part4 live ----
        {
            const unsigned short* we2t = wt + (((size_t)l*6 + 2) << 14);
            const unsigned short* bbase = we2t + lm*128 + quad*8;   // + nt*2048
            #pragma unroll 1
            for (int pass = 0; pass < 2; pass++) {
                bf16x8 wreg[4][4];
                #pragma unroll
                for (int nt = 0; nt < 4; nt++) {
                    #pragma unroll
                    for (int kb = 0; kb < 4; kb++)
                        wreg[nt][kb] = *(const bf16x8*)(bbase + (pass*4 + nt)*2048 + kb*32);
                }
                #pragma unroll 1
                for (int ii = 0; ii < 8; ii++) {
                    const int i = ii*4 + w;               // wave owns row i fully
                    const int cnt = s_cnt[i];             // wave-uniform
                    const int ntile = (cnt > 16) ? 2 : 1; // wave-uniform tile count
                    float part4[4] = {0.f,0.f,0.f,0.f};
#define MAKE_AF(J, KB, AF) { \
    const uint4 miu = *(const uint4*)&s_mimj[i*264 + (KB)*32 + quad*8]; \
    const uint4 mju = *(const uint4*)&s_mimj[(J)*264 + 128 + (KB)*32 + quad*8]; \
    const float4 wa = *(const float4*)&s_wd[(KB)*32 + quad*8]; \
    const float4 wb = *(const float4*)&s_wd[(KB)*32 + quad*8 + 4]; \
    uint4 au; \
    au.x = packbf(silu_f(bflo(miu.x)+bflo(mju.x)+d2v*wa.x), silu_f(bfhi(miu.x)+bfhi(mju.x)+d2v*wa.y)); \
    au.y = packbf(silu_f(bflo(miu.y)+bflo(mju.y)+d2v*wa.z), silu_f(bfhi(miu.y)+bfhi(mju.y)+d2v*wa.w)); \
    au.z = packbf(silu_f(bflo(miu.z)+bflo(mju.z)+d2v*wb.x), silu_f(bfhi(miu.z)+bfhi(mju.z)+d2v*wb.y)); \
    au.w = packbf(silu_f(bflo(miu.w)+bflo(mju.w)+d2v*wb.z), silu_f(bfhi(miu.w)+bfhi(mju.w)+d2v*wb.w)); \
    AF = __builtin_bit_cast(bf16x8, au); }
                    #pragma unroll 1
                    for (int jt = 0; jt < ntile; jt++) {
                        const int j = s_nbr[i][jt*16 + lm];        // gathered neighbor (pad=self)
                        const float d2v = s_nd2[i*32 + jt*16 + lm];
                        bf16x8 a00, a01, a02, a03;
                        MAKE_AF(j, 0, a00) MAKE_AF(j, 1, a01)
                        MAKE_AF(j, 2, a02) MAKE_AF(j, 3, a03)
                        const int jb0 = jt*16 + quad*4;
                        const float mk00 = (jb0 + 0 < cnt) ? 1.f : 0.f;
                        const float mk01 = (jb0 + 1 < cnt) ? 1.f : 0.f;
                        const float mk02 = (jb0 + 2 < cnt) ? 1.f : 0.f;
                        const float mk03 = (jb0 + 3 < cnt) ? 1.f : 0.f;
                        #pragma unroll
                        for (int nt = 0; nt < 4; nt++) {
                            f32x4 ac0 = {0.f,0.f,0.f,0.f};
                            MFMA16(ac0, a00, wreg[nt][0]); MFMA16(ac0, a01, wreg[nt][1]);
                            MFMA16(ac0, a02, wreg[nt][2]); MFMA16(ac0, a03, wreg[nt][3]);
                            const float bv = bf2f(s_be2[(pass*4 + nt)*16 + lm]);
                            part4[nt] += mk00*silu_f(ac0.x + bv) + mk01*silu_f(ac0.y + bv)
                                       + mk02*silu_f(ac0.z + bv) + mk03*silu_f(ac0.w + bv);
                        }
                    }
#undef MAKE_AF
                    #pragma unroll
                    for (int nt = 0; nt < 4; nt++) {
                        float part = part4[nt];
                        part += __shfl_xor(part, 16);
                        part += __shfl_xor(part, 32);
                        if (lane < 16) s_A2[i*136 + (pass*4 + nt)*16 + lane] = f2bf(part);
                    }
                }
            }
        }
        __syncthreads();

        // ---- u = silu(hg@Wh1a + agg@Wh1b + bh1) -> s_u (reuses s_mimj, stride 136) ----
        unsigned short* s_u = s_mimj;
        {
            const unsigned short* w1a = wt + (((size_t)l*6 + 3) << 14);
            const unsigned short* w1b = wt + (((size_t)l*6 + 4) << 14);
#define U_GEMM(T2) { \
    const int nt = ng + (T2)*2, ncl = nt*16 + lm; \
    f32x4 acc = {0.f,0.f,0.f,0.f}; \
    _Pragma("unroll") \
    for (int kb = 0; kb < 4; kb++) { \
        bf16x8 a  = *(const bf16x8*)&s_A1[(mt*16+lm)*136 + kb*32 + quad*8]; \
        bf16x8 bb = *(const bf16x8*)&w1a[ncl*128 + kb*32 + quad*8]; \
        MFMA16(acc, a, bb); } \
    _Pragma("unroll") \
    for (int kb = 0; kb < 4; kb++) { \
        bf16x8 a  = *(const bf16x8*)&s_A2[(mt*16+lm)*136 + kb*32 + quad*8]; \
        bf16x8 bb = *(const bf16x8*)&w1b[ncl*128 + kb*32 + quad*8]; \
        MFMA16(acc, a, bb); } \
    const float bh = bh1[l*128 + ncl]; \
    s_u[(mt*16 + quad*4 + 0)*136 + ncl] = f2bf(silu_f(acc.x + bh)); \
    s_u[(mt*16 + quad*4 + 1)*136 + ncl] = f2bf(silu_f(acc.y + bh)); \
    s_u[(mt*16 + quad*4 + 2)*136 + ncl] = f2bf(silu_f(acc.z + bh)); \
    s_u[(mt*16 + quad*4 + 3)*136 + ncl] = f2bf(silu_f(acc.w + bh)); }
            U_GEMM(0) U_GEMM(1) U_GEMM(2) U_GEMM(3)
#undef U_GEMM
        }
        __syncthreads();

        // ---- hg += u@Wh2 + bh2 (fused: also writes next A1 bf16) ----
        {
            const unsigned short* w2 = wt + (((size_t)l*6 + 5) << 14);
#define H_GEMM(T2) { \
    const int nt = ng + (T2)*2, ncl = nt*16 + lm; \
    f32x4 acc = {0.f,0.f,0.f,0.f}; \
    _Pragma("unroll") \
    for (int kb = 0; kb < 4; kb++) { \
        bf16x8 a  = *(const bf16x8*)&s_u[(mt*16+lm)*136 + kb*32 + quad*8]; \
        bf16x8 bb = *(const bf16x8*)&w2[ncl*128 + kb*32 + quad*8]; \
        MFMA16(acc, a, bb); } \
    const float bh = bh2[l*128 + ncl]; \
    { float v = s_hg[(mt*16 + quad*4 + 0)*129 + ncl] + acc.x + bh; \
      s_hg[(mt*16 + quad*4 + 0)*129 + ncl] = v; s_A1[(mt*16 + quad*4 + 0)*136 + ncl] = f2bf(v); } \
    { float v = s_hg[(mt*16 + quad*4 + 1)*129 + ncl] + acc.y + bh; \
      s_hg[(mt*16 + quad*4 + 1)*129 + ncl] = v; s_A1[(mt*16 + quad*4 + 1)*136 + ncl] = f2bf(v); } \
    { float v = s_hg[(mt*16 + quad*4 + 2)*129 + ncl] + acc.z + bh; \
      s_hg[(mt*16 + quad*4 + 2)*129 + ncl] = v; s_A1[(mt*16 + quad*4 + 2)*136 + ncl] = f2bf(v); } \
    { float v = s_hg[(mt*16 + quad*4 + 3)*129 + ncl] + acc.w + bh; \
      s_hg[(mt*16 + quad*4 + 3)*129 + ncl] = v; s_A1[(mt*16 + quad*4 + 3)*136 + ncl] = f2bf(v); } }
            H_GEMM(0) H_GEMM(1) H_GEMM(2) H_GEMM(3)
#undef H_GEMM
        }
        __syncthreads();
    }

    // ---- output head (A1 already holds bf16(hg) from l=1 H_GEMM) ----
    {   // ho = hg@W_out + b_out -> A2 (bf16)
        const unsigned short* wo = wt + ((size_t)12 << 14);
#define O_GEMM(T2) { \
    const int nt = ng + (T2)*2, ncl = nt*16 + lm; \
    f32x4 acc = {0.f,0.f,0.f,0.f}; \
    _Pragma("unroll") \
    for (int kb = 0; kb < 4; kb++) { \
        bf16x8 a  = *(const bf16x8*)&s_A1[(mt*16+lm)*136 + kb*32 + quad*8]; \
        bf16x8 bb = *(const bf16x8*)&wo[ncl*128 + kb*32 + quad*8]; \
        MFMA16(acc, a, bb); } \
    const float bo = b_out[ncl]; \
    s_A2[(mt*16 + quad*4 + 0)*136 + ncl] = f2bf(acc.x + bo); \
    s_A2[(mt*16 + quad*4 + 1)*136 + ncl] = f2bf(acc.y + bo); \
    s_A2[(mt*16 + quad*4 + 2)*136 + ncl] = f2bf(acc.z + bo); \
    s_A2[(mt*16 + quad*4 + 3)*136 + ncl] = f2bf(acc.w + bo); }
        O_GEMM(0) O_GEMM(1) O_GEMM(2) O_GEMM(3)
#undef O_GEMM
    }
    __syncthreads();
    float* s_g = (float*)s_mimj;                           // reuse (g is 32x129 fp32)
    {   // g = silu(ho@Wn1 + bn1) -> s_g fp32
        const unsigned short* wn1 = wt + ((size_t)13 << 14);
#define G_GEMM(T2) { \
    const int nt = ng + (T2)*2, ncl = nt*16 + lm; \
    f32x4 acc = {0.f,0.f,0.f,0.f}; \
    _Pragma("unroll") \
    for (int kb = 0; kb < 4; kb++) { \
        bf16x8 a  = *(const bf16x8*)&s_A2[(mt*16+lm)*136 + kb*32 + quad*8]; \
        bf16x8 bb = *(const bf16x8*)&wn1[ncl*128 + kb*32 + quad*8]; \
        MFMA16(acc, a, bb); } \
    const float bn = bn1[ncl]; \
    s_g[(mt*16 + quad*4 + 0)*129 + ncl] = silu_f(acc.x + bn); \
    s_g[(mt*16 + quad*4 + 1)*129 + ncl] = silu_f(acc.y + bn); \
    s_g[(mt*16 + quad*4 + 2)*129 + ncl] = silu_f(acc.z + bn); \
    s_g[(mt*16 + quad*4 + 3)*129 + ncl] = silu_f(acc.w + bn); }
        G_GEMM(0) G_GEMM(1) G_GEMM(2) G_GEMM(3)
#undef G_GEMM
    }
    __syncthreads();
    // e = g @ Wn2 + bn2 ; out[b] = sum_m e[m]
    float* s_ep = s_nd2;                                   // reuse (s_nd2 dead)
    {
        int m = tid >> 3, s = tid & 7;
        float acc = 0.f;
        #pragma unroll
        for (int q = 0; q < 16; q++) {
            int hh = s*16 + q;
            acc += s_g[m*129 + hh] * Wn2[hh];
        }
        s_ep[tid] = acc;
    }
    __syncthreads();
    if (tid < 32) {
        float e = bn2[0];
        #pragma unroll
        for (int s = 0; s < 8; s++) e += s_ep[tid*8 + s];
        #pragma unroll
        for (int off = 16; off >= 1; off >>= 1) e += __shfl_down(e, off, 32);
        if (tid == 0) out[b] = e;
    }
}

extern "C" void kernel_launch(void* const* d_in, const int* in_sizes, int n_in,
                              void* d_out, int out_size, void* d_ws, size_t ws_size,
                              hipStream_t stream) {
    const float* h     = (const float*)d_in[0];
    const float* x     = (const float*)d_in[1];
    const float* W_in  = (const float*)d_in[3];
    const float* b_in  = (const float*)d_in[4];
    const float* We1   = (const float*)d_in[5];
    const float* be1   = (const float*)d_in[6];
    const float* We2   = (const float*)d_in[7];
    const float* be2   = (const float*)d_in[8];
    const float* Wh1   = (const float*)d_in[9];
    const float* bh1   = (const float*)d_in[10];
    const float* Wh2   = (const float*)d_in[11];
    const float* bh2   = (const float*)d_in[12];
    const float* W_out = (const float*)d_in[13];
    const float* b_out = (const float*)d_in[14];
    const float* Wn1   = (const float*)d_in[15];
    const float* bn1   = (const float*)d_in[16];
    const float* Wn2   = (const float*)d_in[17];
    const float* bn2   = (const float*)d_in[18];
    unsigned short* ws = (unsigned short*)d_ws;   // needs 14*16384*2 = 448 KB
    float* outp = (float*)d_out;

    prep_weights<<<14*16, 256, 0, stream>>>(We1, We2, Wh1, Wh2, W_out, Wn1, ws);
    sake_kernel<<<NB, 256, 0, stream>>>(h, x, W_in, b_in, We1, be1, be2, bh1, bh2,
                                        b_out, bn1, Wn2, bn2, ws, outp);
}